// Round 1
// baseline (3590.494 us; speedup 1.0000x reference)
//
#include <hip/hip_runtime.h>
#include <cstddef>

#define TT 2048   // time steps
#define BB 256    // batch
#define DD 32     // input dim
#define HH 64     // hidden
#define GG 256    // 4*H gates

__device__ __forceinline__ float sigmf(float v) { return 1.0f / (1.0f + __expf(-v)); }
__device__ __forceinline__ float tanh_f(float v) { return 2.0f / (1.0f + __expf(-2.0f * v)) - 1.0f; }

// One block per batch row. Thread k (0..255) owns gate column k; all weight
// columns held in VGPRs (~227 regs -> __launch_bounds__(256,1) gives 512 budget).
// LDS only for h1/h2/z broadcast. 4 barriers per time step.
__global__ __launch_bounds__(256, 1)
void dlstm_kernel(const float* __restrict__ x,
                  const float* __restrict__ W1, const float* __restrict__ U1,
                  const float* __restrict__ b1,
                  const float* __restrict__ W2, const float* __restrict__ U2,
                  const float* __restrict__ b2,
                  const float* __restrict__ Wd, const float* __restrict__ bd,
                  float* __restrict__ out)
{
    const int k = threadIdx.x;        // gate index 0..255
    const int b = blockIdx.x;         // batch row
    const int wave = k >> 6;          // 0:i 1:f 2:g(tanh) 3:o

    // ---- per-thread weight columns in registers ----
    float w1c[DD], u1c[HH], w2c[HH], u2c[HH];
#pragma unroll
    for (int d = 0; d < DD; ++d) w1c[d] = W1[d * GG + k];
#pragma unroll
    for (int j = 0; j < HH; ++j) u1c[j] = U1[j * GG + k];
#pragma unroll
    for (int j = 0; j < HH; ++j) w2c[j] = W2[j * GG + k];
#pragma unroll
    for (int j = 0; j < HH; ++j) u2c[j] = U2[j * GG + k];

    const float b1k = b1[k], b2k = b2[k];
    const float wdk = (k < HH) ? Wd[k] : 0.0f;
    const float bd0 = bd[0];

    __shared__ __align__(16) float h1b[HH];
    __shared__ __align__(16) float h2b[HH];
    __shared__ __align__(16) float zb[GG];

    float c1 = 0.0f, c2 = 0.0f;
    if (k < HH) { h1b[k] = 0.0f; h2b[k] = 0.0f; }

    const float* xrow = x + (size_t)b * (TT * DD);

    // prefetch x_0 (all lanes same address -> one line, L1/L2 broadcast)
    float4 xv[8];
#pragma unroll
    for (int q = 0; q < 8; ++q) xv[q] = ((const float4*)xrow)[q];

    __syncthreads();

    for (int t = 0; t < TT; ++t) {
        // prefetch x_{t+1}: in flight across the whole step, hides HBM/L2 latency
        const float4* xnp = (const float4*)(xrow + (size_t)((t + 1 < TT) ? t + 1 : t) * DD);
        float4 xn[8];
#pragma unroll
        for (int q = 0; q < 8; ++q) xn[q] = xnp[q];

        // ---- layer-1 gate pre-activation: z1 = b1 + x_t@W1 + h1@U1 ----
        // 4 independent accumulators: FMA dep-chain 4cyc, keeps single wave issue-bound
        float a0 = b1k, a1 = 0.f, a2 = 0.f, a3 = 0.f;
#pragma unroll
        for (int q = 0; q < 8; ++q) {
            a0 += xv[q].x * w1c[4*q+0];
            a1 += xv[q].y * w1c[4*q+1];
            a2 += xv[q].z * w1c[4*q+2];
            a3 += xv[q].w * w1c[4*q+3];
        }
#pragma unroll
        for (int q = 0; q < 16; ++q) {
            float4 hv = ((const float4*)h1b)[q];   // ds_read_b128 broadcast
            a0 += hv.x * u1c[4*q+0];
            a1 += hv.y * u1c[4*q+1];
            a2 += hv.z * u1c[4*q+2];
            a3 += hv.w * u1c[4*q+3];
        }
        float z1 = (a0 + a1) + (a2 + a3);
        zb[k] = (wave == 2) ? tanh_f(z1) : sigmf(z1);
        __syncthreads();

        // ---- layer-1 state update (wave 0 only, uniform branch) ----
        if (k < HH) {
            float gi = zb[k], gf = zb[HH + k], gg = zb[2*HH + k], go = zb[3*HH + k];
            c1 = gf * c1 + gi * gg;
            h1b[k] = go * tanh_f(c1);
        }
        __syncthreads();

        // ---- layer-2: z2 = b2 + h1@W2 + h2@U2 ----
        float d0 = b2k, d1 = 0.f, d2 = 0.f, d3 = 0.f;
#pragma unroll
        for (int q = 0; q < 16; ++q) {
            float4 hv = ((const float4*)h1b)[q];
            d0 += hv.x * w2c[4*q+0];
            d1 += hv.y * w2c[4*q+1];
            d2 += hv.z * w2c[4*q+2];
            d3 += hv.w * w2c[4*q+3];
        }
#pragma unroll
        for (int q = 0; q < 16; ++q) {
            float4 hv = ((const float4*)h2b)[q];
            d0 += hv.x * u2c[4*q+0];
            d1 += hv.y * u2c[4*q+1];
            d2 += hv.z * u2c[4*q+2];
            d3 += hv.w * u2c[4*q+3];
        }
        float z2 = (d0 + d1) + (d2 + d3);
        zb[k] = (wave == 2) ? tanh_f(z2) : sigmf(z2);
        __syncthreads();

        // ---- layer-2 state update + fused output projection (wave 0) ----
        if (k < HH) {
            float gi = zb[k], gf = zb[HH + k], gg = zb[2*HH + k], go = zb[3*HH + k];
            c2 = gf * c2 + gi * gg;
            float h2 = go * tanh_f(c2);
            h2b[k] = h2;
            float v = h2 * wdk;
#pragma unroll
            for (int off = 32; off >= 1; off >>= 1) v += __shfl_down(v, off);
            if (k == 0) out[(size_t)b * TT + t] = sigmf(v + bd0);
        }
        __syncthreads();

#pragma unroll
        for (int q = 0; q < 8; ++q) xv[q] = xn[q];
    }
}

extern "C" void kernel_launch(void* const* d_in, const int* in_sizes, int n_in,
                              void* d_out, int out_size, void* d_ws, size_t ws_size,
                              hipStream_t stream) {
    const float* x  = (const float*)d_in[0];
    const float* W1 = (const float*)d_in[1];
    const float* U1 = (const float*)d_in[2];
    const float* b1 = (const float*)d_in[3];
    const float* W2 = (const float*)d_in[4];
    const float* U2 = (const float*)d_in[5];
    const float* b2 = (const float*)d_in[6];
    const float* Wd = (const float*)d_in[7];
    const float* bd = (const float*)d_in[8];
    float* out = (float*)d_out;

    dlstm_kernel<<<dim3(BB), dim3(256), 0, stream>>>(
        x, W1, U1, b1, W2, U2, b2, Wd, bd, out);
}

// Round 2
// 2215.509 us; speedup vs baseline: 1.6206x; 1.6206x over previous
//
#include <hip/hip_runtime.h>
#include <cstddef>

#define TT 2048   // time steps
#define BB 256    // batch
#define DD 32     // input dim
#define HH 64     // hidden
#define GG 256    // 4*H

__device__ __forceinline__ float sigmf(float v) { return 1.0f / (1.0f + __expf(-v)); }
__device__ __forceinline__ float tanh_f(float v) { return 2.0f / (1.0f + __expf(-2.0f * v)) - 1.0f; }

// One block per batch row; 512 threads = 8 waves.
// Waves 0-3: layer-1 recurrence engine, one step AHEAD.
// Waves 4-7: layer-2 recurrence + output projection, one step behind.
// Thread map within each group: gate g = lane>>4, unit u = 16*wave + (lane&15).
// All 4 gates of a unit are in ONE wave -> state update via 3 shfl_xor, no barrier.
// h1/h2/partials cross via double-buffered LDS; ONE barrier per step.
__global__ __launch_bounds__(512, 2)
void dlstm_kernel(const float* __restrict__ x,
                  const float* __restrict__ W1, const float* __restrict__ U1,
                  const float* __restrict__ b1,
                  const float* __restrict__ W2, const float* __restrict__ U2,
                  const float* __restrict__ b2,
                  const float* __restrict__ Wd, const float* __restrict__ bd,
                  float* __restrict__ out)
{
    const int tid = threadIdx.x;
    const int b   = blockIdx.x;
    const int wid = tid >> 6;       // 0..7
    const int l   = tid & 63;
    const int g   = l >> 4;         // gate 0..3 (i,f,c~,o in Keras order)
    const int uo  = l & 15;

    __shared__ __align__(16) float h1b[2][HH];
    __shared__ __align__(16) float h2b[2][HH];
    __shared__ float pbuf[2][4];

    if (tid < HH) { h1b[0][tid] = 0.f; h1b[1][tid] = 0.f; h2b[0][tid] = 0.f; h2b[1][tid] = 0.f; }
    if (tid < 8) pbuf[tid >> 2][tid & 3] = 0.f;
    __syncthreads();

    if (wid < 4) {
        // ================= layer-1 engine (computes h1(n) at iter n) =================
        const int u   = (wid << 4) + uo;     // 0..63
        const int col = (g << 6) + u;        // column in [0,256), gate-major
        float w1c[DD], u1c[HH];
        #pragma unroll
        for (int d = 0; d < DD; ++d) w1c[d] = W1[d * GG + col];
        #pragma unroll
        for (int j = 0; j < HH; ++j) u1c[j] = U1[j * GG + col];
        const float b1k = b1[col];
        const float bd0 = bd[0];
        float c1 = 0.f;

        const float* xrow = x + (size_t)b * (TT * DD);
        float4 xv[8];
        #pragma unroll
        for (int q = 0; q < 8; ++q) xv[q] = ((const float4*)xrow)[q];

        for (int n = 0; n < TT + 2; ++n) {
            const int p = n & 1;
            if (n < TT) {
                // prefetch x_{n+1} (in flight under the whole step)
                const float4* xnp = (const float4*)(xrow + (size_t)((n + 1 < TT) ? n + 1 : n) * DD);
                float4 xn[8];
                #pragma unroll
                for (int q = 0; q < 8; ++q) xn[q] = xnp[q];

                float a0 = b1k, a1 = 0.f, a2 = 0.f, a3 = 0.f;
                #pragma unroll
                for (int q = 0; q < 8; ++q) {
                    a0 += xv[q].x * w1c[4*q+0];
                    a1 += xv[q].y * w1c[4*q+1];
                    a2 += xv[q].z * w1c[4*q+2];
                    a3 += xv[q].w * w1c[4*q+3];
                }
                const float4* hp = (const float4*)h1b[p];   // h1(n-1), broadcast reads
                #pragma unroll
                for (int q = 0; q < 16; ++q) {
                    float4 hv = hp[q];
                    a0 += hv.x * u1c[4*q+0];
                    a1 += hv.y * u1c[4*q+1];
                    a2 += hv.z * u1c[4*q+2];
                    a3 += hv.w * u1c[4*q+3];
                }
                float z = (a0 + a1) + (a2 + a3);
                float a = (g == 2) ? tanh_f(z) : sigmf(z);
                // intra-wave all-gather of the 4 gates of this unit
                float p16 = __shfl_xor(a, 16, 64);
                float p32 = __shfl_xor(a, 32, 64);
                float p48 = __shfl_xor(p16, 32, 64);
                float gi = (g==0) ? a   : (g==1) ? p16 : (g==2) ? p32 : p48;
                float gf = (g==0) ? p16 : (g==1) ? a   : (g==2) ? p48 : p32;
                float gc = (g==0) ? p32 : (g==1) ? p48 : (g==2) ? a   : p16;
                float go = (g==0) ? p48 : (g==1) ? p32 : (g==2) ? p16 : a;
                c1 = gf * c1 + gi * gc;
                float h = go * tanh_f(c1);
                if (g == 0) h1b[p ^ 1][u] = h;

                #pragma unroll
                for (int q = 0; q < 8; ++q) xv[q] = xn[q];
            }
            // output store: out(n-2) from partials written by B at iter n-1
            if (tid == 0 && n >= 2) {
                float s = pbuf[p][0] + pbuf[p][1] + pbuf[p][2] + pbuf[p][3];
                out[(size_t)b * TT + (n - 2)] = sigmf(s + bd0);
            }
            __syncthreads();
        }
    } else {
        // ================= layer-2 engine (computes h2(n-1) at iter n) =================
        const int w2i = wid - 4;
        const int u   = (w2i << 4) + uo;
        const int col = (g << 6) + u;
        float w2c[HH], u2c[HH];
        #pragma unroll
        for (int j = 0; j < HH; ++j) w2c[j] = W2[j * GG + col];
        #pragma unroll
        for (int j = 0; j < HH; ++j) u2c[j] = U2[j * GG + col];
        const float b2k = b2[col];
        const float wdk = Wd[u];
        float c2 = 0.f;

        for (int n = 0; n < TT + 2; ++n) {
            const int p = n & 1;
            if (n >= 1 && n <= TT) {
                float d0 = b2k, d1 = 0.f, d2 = 0.f, d3 = 0.f;
                const float4* h1p = (const float4*)h1b[p];  // h1(n-1)
                const float4* h2p = (const float4*)h2b[p];  // h2(n-2)
                #pragma unroll
                for (int q = 0; q < 16; ++q) {
                    float4 hv = h1p[q];
                    d0 += hv.x * w2c[4*q+0];
                    d1 += hv.y * w2c[4*q+1];
                    d2 += hv.z * w2c[4*q+2];
                    d3 += hv.w * w2c[4*q+3];
                }
                #pragma unroll
                for (int q = 0; q < 16; ++q) {
                    float4 hv = h2p[q];
                    d0 += hv.x * u2c[4*q+0];
                    d1 += hv.y * u2c[4*q+1];
                    d2 += hv.z * u2c[4*q+2];
                    d3 += hv.w * u2c[4*q+3];
                }
                float z = (d0 + d1) + (d2 + d3);
                float a = (g == 2) ? tanh_f(z) : sigmf(z);
                float p16 = __shfl_xor(a, 16, 64);
                float p32 = __shfl_xor(a, 32, 64);
                float p48 = __shfl_xor(p16, 32, 64);
                float gi = (g==0) ? a   : (g==1) ? p16 : (g==2) ? p32 : p48;
                float gf = (g==0) ? p16 : (g==1) ? a   : (g==2) ? p48 : p32;
                float gc = (g==0) ? p32 : (g==1) ? p48 : (g==2) ? a   : p16;
                float go = (g==0) ? p48 : (g==1) ? p32 : (g==2) ? p16 : a;
                c2 = gf * c2 + gi * gc;
                float h = go * tanh_f(c2);
                if (g == 0) h2b[p ^ 1][u] = h;
                // projection partial for out(n-1): sum over this wave's 16 units
                float v = (g == 0) ? h * wdk : 0.f;
                v += __shfl_xor(v, 1, 64);
                v += __shfl_xor(v, 2, 64);
                v += __shfl_xor(v, 4, 64);
                v += __shfl_xor(v, 8, 64);
                if (l == 0) pbuf[p ^ 1][w2i] = v;
            }
            __syncthreads();
        }
    }
}

extern "C" void kernel_launch(void* const* d_in, const int* in_sizes, int n_in,
                              void* d_out, int out_size, void* d_ws, size_t ws_size,
                              hipStream_t stream) {
    const float* x  = (const float*)d_in[0];
    const float* W1 = (const float*)d_in[1];
    const float* U1 = (const float*)d_in[2];
    const float* b1 = (const float*)d_in[3];
    const float* W2 = (const float*)d_in[4];
    const float* U2 = (const float*)d_in[5];
    const float* b2 = (const float*)d_in[6];
    const float* Wd = (const float*)d_in[7];
    const float* bd = (const float*)d_in[8];
    float* out = (float*)d_out;

    dlstm_kernel<<<dim3(BB), dim3(512), 0, stream>>>(
        x, W1, U1, b1, W2, U2, b2, Wd, bd, out);
}

// Round 3
// 2145.602 us; speedup vs baseline: 1.6734x; 1.0326x over previous
//
#include <hip/hip_runtime.h>
#include <cstddef>

#define TT 2048   // time steps
#define BB 256    // batch
#define DD 32     // input dim
#define HH 64     // hidden
#define GG 256    // 4*H

__device__ __forceinline__ float sigmf(float v) { return 1.0f / (1.0f + __expf(-v)); }
__device__ __forceinline__ float tanh_f(float v) { return 2.0f / (1.0f + __expf(-2.0f * v)) - 1.0f; }

// Pin a value into an arch-VGPR: opaque asm prevents rematerialization,
// AGPR-shuttling, and scratch demotion of the loop-invariant weights.
#define PIN(x) asm volatile("" : "+v"(x))

// One block per batch row; 512 threads = 8 waves.
// Waves 0-3: layer-1 recurrence engine, one step AHEAD.
// Waves 4-7: layer-2 recurrence + output projection, one step behind.
// Thread map within each group: gate g = lane>>4, unit u = 16*wave + (lane&15).
// All 4 gates of a unit are in ONE wave -> state update via 3 shfl_xor, no barrier.
// h1/h2/partials cross via double-buffered LDS; ONE barrier per step.
__global__ __launch_bounds__(512, 2)
void dlstm_kernel(const float* __restrict__ x,
                  const float* __restrict__ W1, const float* __restrict__ U1,
                  const float* __restrict__ b1,
                  const float* __restrict__ W2, const float* __restrict__ U2,
                  const float* __restrict__ b2,
                  const float* __restrict__ Wd, const float* __restrict__ bd,
                  float* __restrict__ out)
{
    const int tid = threadIdx.x;
    const int b   = blockIdx.x;
    const int wid = tid >> 6;       // 0..7
    const int l   = tid & 63;
    const int g   = l >> 4;         // gate 0..3 (i,f,c~,o in Keras order)
    const int uo  = l & 15;

    __shared__ __align__(16) float h1b[2][HH];
    __shared__ __align__(16) float h2b[2][HH];
    __shared__ float pbuf[2][4];

    if (tid < HH) { h1b[0][tid] = 0.f; h1b[1][tid] = 0.f; h2b[0][tid] = 0.f; h2b[1][tid] = 0.f; }
    if (tid < 8) pbuf[tid >> 2][tid & 3] = 0.f;
    __syncthreads();

    if (wid < 4) {
        // ================= layer-1 engine (computes h1(n) at iter n) =================
        const int u   = (wid << 4) + uo;     // 0..63
        const int col = (g << 6) + u;        // column in [0,256), gate-major
        float w1c[DD], u1c[HH];
        #pragma unroll
        for (int d = 0; d < DD; ++d) w1c[d] = W1[d * GG + col];
        #pragma unroll
        for (int j = 0; j < HH; ++j) u1c[j] = U1[j * GG + col];
        #pragma unroll
        for (int d = 0; d < DD; ++d) PIN(w1c[d]);
        #pragma unroll
        for (int j = 0; j < HH; ++j) PIN(u1c[j]);
        const float b1k = b1[col];
        const float bd0 = bd[0];
        float c1 = 0.f;

        const float* xrow = x + (size_t)b * (TT * DD);
        float4 xv[8];
        #pragma unroll
        for (int q = 0; q < 8; ++q) xv[q] = ((const float4*)xrow)[q];

        #pragma unroll 2
        for (int n = 0; n < TT + 2; ++n) {
            const int p = n & 1;
            if (n < TT) {
                // prefetch x_{n+1} (in flight under the whole step)
                const float4* xnp = (const float4*)(xrow + (size_t)((n + 1 < TT) ? n + 1 : n) * DD);
                float4 xn[8];
                #pragma unroll
                for (int q = 0; q < 8; ++q) xn[q] = xnp[q];

                float a0 = b1k, a1 = 0.f, a2 = 0.f, a3 = 0.f;
                #pragma unroll
                for (int q = 0; q < 8; ++q) {
                    a0 += xv[q].x * w1c[4*q+0];
                    a1 += xv[q].y * w1c[4*q+1];
                    a2 += xv[q].z * w1c[4*q+2];
                    a3 += xv[q].w * w1c[4*q+3];
                }
                const float4* hp = (const float4*)h1b[p];   // h1(n-1), broadcast reads
                #pragma unroll
                for (int q = 0; q < 16; ++q) {
                    float4 hv = hp[q];
                    a0 += hv.x * u1c[4*q+0];
                    a1 += hv.y * u1c[4*q+1];
                    a2 += hv.z * u1c[4*q+2];
                    a3 += hv.w * u1c[4*q+3];
                }
                float z = (a0 + a1) + (a2 + a3);
                float a = (g == 2) ? tanh_f(z) : sigmf(z);
                // intra-wave all-gather of the 4 gates of this unit
                float p16 = __shfl_xor(a, 16, 64);
                float p32 = __shfl_xor(a, 32, 64);
                float p48 = __shfl_xor(p16, 32, 64);
                float gi = (g==0) ? a   : (g==1) ? p16 : (g==2) ? p32 : p48;
                float gf = (g==0) ? p16 : (g==1) ? a   : (g==2) ? p48 : p32;
                float gc = (g==0) ? p32 : (g==1) ? p48 : (g==2) ? a   : p16;
                float go = (g==0) ? p48 : (g==1) ? p32 : (g==2) ? p16 : a;
                c1 = gf * c1 + gi * gc;
                float h = go * tanh_f(c1);
                if (g == 0) h1b[p ^ 1][u] = h;

                #pragma unroll
                for (int q = 0; q < 8; ++q) xv[q] = xn[q];
            }
            // output store: out(n-2) from partials written by B at iter n-1
            if (tid == 0 && n >= 2) {
                float s = pbuf[p][0] + pbuf[p][1] + pbuf[p][2] + pbuf[p][3];
                out[(size_t)b * TT + (n - 2)] = sigmf(s + bd0);
            }
            __syncthreads();
        }
    } else {
        // ================= layer-2 engine (computes h2(n-1) at iter n) =================
        const int w2i = wid - 4;
        const int u   = (w2i << 4) + uo;
        const int col = (g << 6) + u;
        float w2c[HH], u2c[HH];
        #pragma unroll
        for (int j = 0; j < HH; ++j) w2c[j] = W2[j * GG + col];
        #pragma unroll
        for (int j = 0; j < HH; ++j) u2c[j] = U2[j * GG + col];
        #pragma unroll
        for (int j = 0; j < HH; ++j) PIN(w2c[j]);
        #pragma unroll
        for (int j = 0; j < HH; ++j) PIN(u2c[j]);
        const float b2k = b2[col];
        const float wdk = Wd[u];
        float c2 = 0.f;

        #pragma unroll 2
        for (int n = 0; n < TT + 2; ++n) {
            const int p = n & 1;
            if (n >= 1 && n <= TT) {
                float d0 = b2k, d1 = 0.f, d2 = 0.f, d3 = 0.f;
                const float4* h1p = (const float4*)h1b[p];  // h1(n-1)
                const float4* h2p = (const float4*)h2b[p];  // h2(n-2)
                #pragma unroll
                for (int q = 0; q < 16; ++q) {
                    float4 hv = h1p[q];
                    d0 += hv.x * w2c[4*q+0];
                    d1 += hv.y * w2c[4*q+1];
                    d2 += hv.z * w2c[4*q+2];
                    d3 += hv.w * w2c[4*q+3];
                }
                #pragma unroll
                for (int q = 0; q < 16; ++q) {
                    float4 hv = h2p[q];
                    d0 += hv.x * u2c[4*q+0];
                    d1 += hv.y * u2c[4*q+1];
                    d2 += hv.z * u2c[4*q+2];
                    d3 += hv.w * u2c[4*q+3];
                }
                float z = (d0 + d1) + (d2 + d3);
                float a = (g == 2) ? tanh_f(z) : sigmf(z);
                float p16 = __shfl_xor(a, 16, 64);
                float p32 = __shfl_xor(a, 32, 64);
                float p48 = __shfl_xor(p16, 32, 64);
                float gi = (g==0) ? a   : (g==1) ? p16 : (g==2) ? p32 : p48;
                float gf = (g==0) ? p16 : (g==1) ? a   : (g==2) ? p48 : p32;
                float gc = (g==0) ? p32 : (g==1) ? p48 : (g==2) ? a   : p16;
                float go = (g==0) ? p48 : (g==1) ? p32 : (g==2) ? p16 : a;
                c2 = gf * c2 + gi * gc;
                float h = go * tanh_f(c2);
                if (g == 0) h2b[p ^ 1][u] = h;
                // projection partial for out(n-1): sum over this wave's 16 units
                float v = (g == 0) ? h * wdk : 0.f;
                v += __shfl_xor(v, 1, 64);
                v += __shfl_xor(v, 2, 64);
                v += __shfl_xor(v, 4, 64);
                v += __shfl_xor(v, 8, 64);
                if (l == 0) pbuf[p ^ 1][w2i] = v;
            }
            __syncthreads();
        }
    }
}

extern "C" void kernel_launch(void* const* d_in, const int* in_sizes, int n_in,
                              void* d_out, int out_size, void* d_ws, size_t ws_size,
                              hipStream_t stream) {
    const float* x  = (const float*)d_in[0];
    const float* W1 = (const float*)d_in[1];
    const float* U1 = (const float*)d_in[2];
    const float* b1 = (const float*)d_in[3];
    const float* W2 = (const float*)d_in[4];
    const float* U2 = (const float*)d_in[5];
    const float* b2 = (const float*)d_in[6];
    const float* Wd = (const float*)d_in[7];
    const float* bd = (const float*)d_in[8];
    float* out = (float*)d_out;

    dlstm_kernel<<<dim3(BB), dim3(512), 0, stream>>>(
        x, W1, U1, b1, W2, U2, b2, Wd, bd, out);
}